// Round 6
// baseline (266.907 us; speedup 1.0000x reference)
//
#include <hip/hip_runtime.h>
#include <cstddef>

#define BATCH 4
#define SEQ   4096
#define DIM   2048
#define EPSF  1e-5f
#define TCHUNK 16
#define CPB   (SEQ / TCHUNK)         // 256 mask chunks per batch
#define NBLK  (BATCH * CPB)          // 1024 mask blocks
#define SROWS 8                      // rows per scatter block
#define NSCAT (BATCH * (SEQ / SROWS))// 2048 scatter blocks

typedef float f4 __attribute__((ext_vector_type(4)));

__device__ __forceinline__ float wave_sum(float v) {
#pragma unroll
    for (int off = 32; off > 0; off >>= 1)
        v += __shfl_down(v, off, 64);
    return v;
}
__device__ __forceinline__ int wave_sum_i(int v) {
#pragma unroll
    for (int off = 32; off > 0; off >>= 1)
        v += __shfl_down(v, off, 64);
    return v;
}

// Phase 1: fused rmsnorm -> causal depthwise conv(W=4) -> silu -> (p1-p0) dot
// -> sign. Same arithmetic as the proven 265us kernel; TCHUNK widened 8->16:
//  - warm-up overfetch 1.375x -> 1.19x  (-25 MB traffic)
//  - barriers per token halved (6 per 16 tokens vs 4 per 8)
//  - 1024 blocks at 4/CU (launch_bounds(256,4), ~120 VGPR live set) = ONE
//    full residency generation, no occupancy tail.
// Blocks fully independent (round-1 lookback showed coupling costs ~150us).
// Output: one packed u32 per chunk: cnt[chunk] = count | (mask_bits16 << 16).
__global__ __launch_bounds__(256, 4) void mask_kernel(
    const float* __restrict__ x, const float* __restrict__ nw,
    const float* __restrict__ cw, const float* __restrict__ pw,
    unsigned int* __restrict__ cnt)
{
    __shared__ float lds_ss[5][4][4];   // slots 0..3 = groups, 4 = warmup
    __shared__ float lds_acc[4][4][4];  // write-once slots -> no WAR hazards

    const int t = threadIdx.x, lane = t & 63, wid = t >> 6;
    // XCD swizzle: seq-adjacent chunks -> same XCD (L2 reuse of warm-up rows)
    const int G = gridDim.x;
    const int chunk = (blockIdx.x & 7) * (G >> 3) + (blockIdx.x >> 3);
    const int b  = chunk / CPB;
    const int s0 = (chunk % CPB) * TCHUNK;
    const int d0 = 4 * t, d1 = d0 + 1024;

    // conv*norm folded (cwn), projection diff (pd)
    float cwn[8][4], pd[8];
    {
        float4 n0 = *(const float4*)(nw + d0);
        float4 n1 = *(const float4*)(nw + d1);
        float nv[8] = {n0.x, n0.y, n0.z, n0.w, n1.x, n1.y, n1.z, n1.w};
#pragma unroll
        for (int i = 0; i < 8; ++i) {
            const int d = (i < 4) ? (d0 + i) : (d1 + i - 4);
            float4 c4 = *(const float4*)(cw + 4 * d);
            cwn[i][0] = c4.x * nv[i]; cwn[i][1] = c4.y * nv[i];
            cwn[i][2] = c4.z * nv[i]; cwn[i][3] = c4.w * nv[i];
        }
        float4 a0 = *(const float4*)(pw + d0);
        float4 a1 = *(const float4*)(pw + d1);
        float4 b0 = *(const float4*)(pw + DIM + d0);
        float4 b1 = *(const float4*)(pw + DIM + d1);
        pd[0] = b0.x - a0.x; pd[1] = b0.y - a0.y; pd[2] = b0.z - a0.z; pd[3] = b0.w - a0.w;
        pd[4] = b1.x - a1.x; pd[5] = b1.y - a1.y; pd[6] = b1.z - a1.z; pd[7] = b1.w - a1.w;
    }

    const float* xb = x + (size_t)b * SEQ * DIM;
    float h1[8], h2[8], h3[8];   // normalized rows s-1, s-2, s-3

    // ---- warm-up: tokens s0-3..s0-1 (1 barrier) ----
    {
        float wv[3][8];
#pragma unroll
        for (int w = 0; w < 3; ++w) {
            const int s = s0 - 3 + w;
            if (s >= 0) {
                float4 a = *(const float4*)(xb + (size_t)s * DIM + d0);
                float4 c = *(const float4*)(xb + (size_t)s * DIM + d1);
                wv[w][0]=a.x; wv[w][1]=a.y; wv[w][2]=a.z; wv[w][3]=a.w;
                wv[w][4]=c.x; wv[w][5]=c.y; wv[w][6]=c.z; wv[w][7]=c.w;
            } else {
#pragma unroll
                for (int i = 0; i < 8; ++i) wv[w][i] = 0.f;
            }
            float ss = 0.f;
#pragma unroll
            for (int i = 0; i < 8; ++i) ss += wv[w][i] * wv[w][i];
            ss = wave_sum(ss);
            if (lane == 0) lds_ss[4][w][wid] = ss;
        }
        __syncthreads();
#pragma unroll
        for (int w = 0; w < 3; ++w) {
            const float sum4 = lds_ss[4][w][0] + lds_ss[4][w][1]
                             + lds_ss[4][w][2] + lds_ss[4][w][3];
            const float rstd = 1.0f / sqrtf(sum4 * (1.0f / DIM) + EPSF);
            float* h = (w == 0) ? h3 : (w == 1) ? h2 : h1;
#pragma unroll
            for (int i = 0; i < 8; ++i) h[i] = wv[w][i] * rstd;
        }
    }

    // ---- main: 4 groups of 4 tokens, 1 barrier each + 1 final ----
#pragma unroll
    for (int g = 0; g < 4; ++g) {
        float xv[4][8];
#pragma unroll
        for (int j = 0; j < 4; ++j) {
            const int s = s0 + 4 * g + j;
            float4 a = *(const float4*)(xb + (size_t)s * DIM + d0);
            float4 c = *(const float4*)(xb + (size_t)s * DIM + d1);
            xv[j][0]=a.x; xv[j][1]=a.y; xv[j][2]=a.z; xv[j][3]=a.w;
            xv[j][4]=c.x; xv[j][5]=c.y; xv[j][6]=c.z; xv[j][7]=c.w;
        }
#pragma unroll
        for (int j = 0; j < 4; ++j) {
            float ss = 0.f;
#pragma unroll
            for (int i = 0; i < 8; ++i) ss += xv[j][i] * xv[j][i];
            ss = wave_sum(ss);
            if (lane == 0) lds_ss[g][j][wid] = ss;
        }
        __syncthreads();   // orders this group's ss writes
#pragma unroll
        for (int j = 0; j < 4; ++j) {
            const float sum4 = lds_ss[g][j][0] + lds_ss[g][j][1]
                             + lds_ss[g][j][2] + lds_ss[g][j][3];
            const float rstd = 1.0f / sqrtf(sum4 * (1.0f / DIM) + EPSF);
            float acc = 0.f;
#pragma unroll
            for (int i = 0; i < 8; ++i) {
                const float hc = xv[j][i] * rstd;
                const float y = cwn[i][0] * h3[i] + cwn[i][1] * h2[i]
                              + cwn[i][2] * h1[i] + cwn[i][3] * hc;
                const float sig = 1.0f / (1.0f + __expf(-y));
                acc += (y * sig) * pd[i];
                h3[i] = h2[i]; h2[i] = h1[i]; h1[i] = hc;
            }
            acc = wave_sum(acc);
            if (lane == 0) lds_acc[g][j][wid] = acc;
        }
    }
    __syncthreads();   // final: all 4 groups' acc slots visible

    // ---- pack 16 signs + count into one u32 (wave 0 only) ----
    if (wid == 0) {
        int sel = 0;
        if (lane < 16) {
            const int g = lane >> 2, j = lane & 3;
            const float a = lds_acc[g][j][0] + lds_acc[g][j][1]
                          + lds_acc[g][j][2] + lds_acc[g][j][3];
            sel = (a > 0.f) ? 1 : 0;   // lane = token offset in chunk
        }
        const unsigned long long bal = __ballot(sel);
        if (lane == 0)
            cnt[chunk] = (unsigned)__popcll(bal)
                       | ((unsigned)(bal & 0xFFFFull) << 16);
    }
}

// Phase 2 (scan+scatter fused): one block per 8-row half-chunk. Each block
// rebuilds its exclusive prefix + batch total from the 256 per-batch chunk
// counts (1 KB, L2-hot; one count per thread, packed reduce gives prefix AND
// nsel at once). x loads for selected rows are issued BEFORE the reduce (their
// addresses depend only on this chunk's bits, one uniform scalar load), hiding
// L3/HBM latency under the reduction. out is write-once -> nontemporal stores
// (no write-allocate, keeps x L3-resident). Bijection onto [0,S): selected ->
// p-1, unselected -> nsel + s - p.
__global__ __launch_bounds__(256, 4) void scatter_kernel(
    const float* __restrict__ x, const unsigned int* __restrict__ cnt,
    float* __restrict__ out)
{
    __shared__ unsigned int lds_r[4];
    const int blk  = blockIdx.x;
    const int b    = blk >> 9;            // 512 scatter blocks per batch
    const int c8   = blk & 511;
    const int mc   = c8 >> 1;             // owning mask chunk (0..255)
    const int hf   = c8 & 1;              // which 8-token half
    const int t = threadIdx.x, lane = t & 63, wid = t >> 6;

    const unsigned int* cb = cnt + b * CPB;
    const unsigned vown   = cb[mc];                 // uniform -> scalar load
    const unsigned bits16 = vown >> 16;
    const unsigned bits   = (bits16 >> (8 * hf)) & 0xFFu;

    // issue the count load for the reduce (one per thread, covers all 256) ...
    const unsigned u = cb[t];

    // ... and the selected x rows, before the reduce completes
    const int s0 = c8 * SROWS;
    const float* xb = x + (size_t)b * SEQ * DIM;
    const int d0 = 4 * t, d1 = d0 + 1024;
    const float4 z = make_float4(0.f, 0.f, 0.f, 0.f);
    float4 ra[SROWS], rc[SROWS];
#pragma unroll
    for (int j = 0; j < SROWS; ++j) {
        if ((bits >> j) & 1) {                 // uniform branch
            const float* src = xb + (size_t)(s0 + j) * DIM;
            ra[j] = *(const float4*)(src + d0);
            rc[j] = *(const float4*)(src + d1);
        } else { ra[j] = z; rc[j] = z; }
    }

    // packed reduce: low16 = exclusive-prefix contribution, high16 = total
    const int c = (int)(u & 0xFFFFu);
    int pack = ((t < mc) ? c : 0) + (c << 16);
    pack = wave_sum_i(pack);
    if (lane == 0) lds_r[wid] = (unsigned)pack;
    __syncthreads();
    const unsigned tot = lds_r[0] + lds_r[1] + lds_r[2] + lds_r[3];
    const int pre  = (int)(tot & 0xFFFFu)
                   + (hf ? __popc(bits16 & 0xFFu) : 0);
    const int nsel = (int)(tot >> 16);

    float* ob = out + (size_t)b * SEQ * DIM;
#pragma unroll
    for (int j = 0; j < SROWS; ++j) {
        const int incl = __popc(bits & ((2u << j) - 1u));   // inclusive in 8
        const int p    = pre + incl;
        const int sel  = (bits >> j) & 1;
        const int dest = sel ? (p - 1) : (nsel + s0 + j - p);
        float* o = ob + (size_t)dest * DIM;
        __builtin_nontemporal_store(*(const f4*)&ra[j], (f4*)(o + d0));
        __builtin_nontemporal_store(*(const f4*)&rc[j], (f4*)(o + d1));
    }
}

extern "C" void kernel_launch(void* const* d_in, const int* in_sizes, int n_in,
                              void* d_out, int out_size, void* d_ws, size_t ws_size,
                              hipStream_t stream) {
    const float* x  = (const float*)d_in[0];   // [B,S,D]
    const float* nw = (const float*)d_in[1];   // [D]
    const float* cw = (const float*)d_in[2];   // [D,4]
    const float* pw = (const float*)d_in[3];   // [2,D]
    float* out = (float*)d_out;                // [B,S,D]

    unsigned int* cnt = (unsigned int*)d_ws;   // NBLK u32 = 4 KB; every entry
                                               // written by mask before scatter
                                               // reads -> no memset needed
    mask_kernel<<<NBLK, 256, 0, stream>>>(x, nw, cw, pw, cnt);
    scatter_kernel<<<NSCAT, 256, 0, stream>>>(x, cnt, out);
}

// Round 8
// 263.205 us; speedup vs baseline: 1.0141x; 1.0141x over previous
//
#include <hip/hip_runtime.h>
#include <cstddef>

#define BATCH 4
#define SEQ   4096
#define DIM   2048
#define EPSF  1e-5f
#define TCHUNK 16
#define CPB   (SEQ / TCHUNK)         // 256 mask chunks per batch
#define NBLK  (BATCH * CPB)          // 1024 mask blocks
#define SROWS 8                      // rows per scatter block
#define NSCAT (BATCH * (SEQ / SROWS))// 2048 scatter blocks

typedef float f4 __attribute__((ext_vector_type(4)));

__device__ __forceinline__ float wave_sum(float v) {
#pragma unroll
    for (int off = 32; off > 0; off >>= 1)
        v += __shfl_down(v, off, 64);
    return v;
}
__device__ __forceinline__ int wave_sum_i(int v) {
#pragma unroll
    for (int off = 32; off > 0; off >>= 1)
        v += __shfl_down(v, off, 64);
    return v;
}

// Phase 1: fused rmsnorm -> causal depthwise conv(W=4) -> silu -> (p1-p0) dot
// -> sign. TCHUNK=16 (overfetch 1.19x, verified: 88 MB HBM fetch in r6).
// launch_bounds(256,3): round-6 showed (256,4) clamps VGPR to 64 and spills
// ~21 MB of scratch traffic (mask 81.6us, WRITE_SIZE 21.5MB for a 4KB
// output). (256,3) is the round-0-proven budget (~128+ VGPR, no spill,
// 12 waves/CU).
// Blocks fully independent (round-1 lookback showed coupling costs ~150us).
// Output: one packed u32 per chunk: cnt[chunk] = count | (mask_bits16 << 16).
__global__ __launch_bounds__(256, 3) void mask_kernel(
    const float* __restrict__ x, const float* __restrict__ nw,
    const float* __restrict__ cw, const float* __restrict__ pw,
    unsigned int* __restrict__ cnt)
{
    __shared__ float lds_ss[5][4][4];   // slots 0..3 = groups, 4 = warmup
    __shared__ float lds_acc[4][4][4];  // write-once slots -> no WAR hazards

    const int t = threadIdx.x, lane = t & 63, wid = t >> 6;
    // XCD swizzle: seq-adjacent chunks -> same XCD (L2 reuse of warm-up rows)
    const int G = gridDim.x;
    const int chunk = (blockIdx.x & 7) * (G >> 3) + (blockIdx.x >> 3);
    const int b  = chunk / CPB;
    const int s0 = (chunk % CPB) * TCHUNK;
    const int d0 = 4 * t, d1 = d0 + 1024;

    // conv*norm folded (cwn), projection diff (pd)
    float cwn[8][4], pd[8];
    {
        float4 n0 = *(const float4*)(nw + d0);
        float4 n1 = *(const float4*)(nw + d1);
        float nv[8] = {n0.x, n0.y, n0.z, n0.w, n1.x, n1.y, n1.z, n1.w};
#pragma unroll
        for (int i = 0; i < 8; ++i) {
            const int d = (i < 4) ? (d0 + i) : (d1 + i - 4);
            float4 c4 = *(const float4*)(cw + 4 * d);
            cwn[i][0] = c4.x * nv[i]; cwn[i][1] = c4.y * nv[i];
            cwn[i][2] = c4.z * nv[i]; cwn[i][3] = c4.w * nv[i];
        }
        float4 a0 = *(const float4*)(pw + d0);
        float4 a1 = *(const float4*)(pw + d1);
        float4 b0 = *(const float4*)(pw + DIM + d0);
        float4 b1 = *(const float4*)(pw + DIM + d1);
        pd[0] = b0.x - a0.x; pd[1] = b0.y - a0.y; pd[2] = b0.z - a0.z; pd[3] = b0.w - a0.w;
        pd[4] = b1.x - a1.x; pd[5] = b1.y - a1.y; pd[6] = b1.z - a1.z; pd[7] = b1.w - a1.w;
    }

    const float* xb = x + (size_t)b * SEQ * DIM;
    float h1[8], h2[8], h3[8];   // normalized rows s-1, s-2, s-3

    // ---- warm-up: tokens s0-3..s0-1 (1 barrier) ----
    {
        float wv[3][8];
#pragma unroll
        for (int w = 0; w < 3; ++w) {
            const int s = s0 - 3 + w;
            if (s >= 0) {
                float4 a = *(const float4*)(xb + (size_t)s * DIM + d0);
                float4 c = *(const float4*)(xb + (size_t)s * DIM + d1);
                wv[w][0]=a.x; wv[w][1]=a.y; wv[w][2]=a.z; wv[w][3]=a.w;
                wv[w][4]=c.x; wv[w][5]=c.y; wv[w][6]=c.z; wv[w][7]=c.w;
            } else {
#pragma unroll
                for (int i = 0; i < 8; ++i) wv[w][i] = 0.f;
            }
            float ss = 0.f;
#pragma unroll
            for (int i = 0; i < 8; ++i) ss += wv[w][i] * wv[w][i];
            ss = wave_sum(ss);
            if (lane == 0) lds_ss[4][w][wid] = ss;
        }
        __syncthreads();
#pragma unroll
        for (int w = 0; w < 3; ++w) {
            const float sum4 = lds_ss[4][w][0] + lds_ss[4][w][1]
                             + lds_ss[4][w][2] + lds_ss[4][w][3];
            const float rstd = 1.0f / sqrtf(sum4 * (1.0f / DIM) + EPSF);
            float* h = (w == 0) ? h3 : (w == 1) ? h2 : h1;
#pragma unroll
            for (int i = 0; i < 8; ++i) h[i] = wv[w][i] * rstd;
        }
    }

    // ---- main: 4 groups of 4 tokens, 1 barrier each + 1 final ----
#pragma unroll
    for (int g = 0; g < 4; ++g) {
        float xv[4][8];
#pragma unroll
        for (int j = 0; j < 4; ++j) {
            const int s = s0 + 4 * g + j;
            float4 a = *(const float4*)(xb + (size_t)s * DIM + d0);
            float4 c = *(const float4*)(xb + (size_t)s * DIM + d1);
            xv[j][0]=a.x; xv[j][1]=a.y; xv[j][2]=a.z; xv[j][3]=a.w;
            xv[j][4]=c.x; xv[j][5]=c.y; xv[j][6]=c.z; xv[j][7]=c.w;
        }
#pragma unroll
        for (int j = 0; j < 4; ++j) {
            float ss = 0.f;
#pragma unroll
            for (int i = 0; i < 8; ++i) ss += xv[j][i] * xv[j][i];
            ss = wave_sum(ss);
            if (lane == 0) lds_ss[g][j][wid] = ss;
        }
        __syncthreads();   // orders this group's ss writes
#pragma unroll
        for (int j = 0; j < 4; ++j) {
            const float sum4 = lds_ss[g][j][0] + lds_ss[g][j][1]
                             + lds_ss[g][j][2] + lds_ss[g][j][3];
            const float rstd = 1.0f / sqrtf(sum4 * (1.0f / DIM) + EPSF);
            float acc = 0.f;
#pragma unroll
            for (int i = 0; i < 8; ++i) {
                const float hc = xv[j][i] * rstd;
                const float y = cwn[i][0] * h3[i] + cwn[i][1] * h2[i]
                              + cwn[i][2] * h1[i] + cwn[i][3] * hc;
                const float sig = 1.0f / (1.0f + __expf(-y));
                acc += (y * sig) * pd[i];
                h3[i] = h2[i]; h2[i] = h1[i]; h1[i] = hc;
            }
            acc = wave_sum(acc);
            if (lane == 0) lds_acc[g][j][wid] = acc;
        }
    }
    __syncthreads();   // final: all 4 groups' acc slots visible

    // ---- pack 16 signs + count into one u32 (wave 0 only) ----
    if (wid == 0) {
        int sel = 0;
        if (lane < 16) {
            const int g = lane >> 2, j = lane & 3;
            const float a = lds_acc[g][j][0] + lds_acc[g][j][1]
                          + lds_acc[g][j][2] + lds_acc[g][j][3];
            sel = (a > 0.f) ? 1 : 0;   // lane = token offset in chunk
        }
        const unsigned long long bal = __ballot(sel);
        if (lane == 0)
            cnt[chunk] = (unsigned)__popcll(bal)
                       | ((unsigned)(bal & 0xFFFFull) << 16);
    }
}

// Phase 2 (scan+scatter fused): one block per 8-row half-chunk. Each block
// rebuilds its exclusive prefix + batch total from the 256 per-batch chunk
// counts (1 KB, L2-hot; one count per thread, packed reduce gives prefix AND
// nsel at once). x loads for selected rows are issued BEFORE the reduce (their
// addresses depend only on this chunk's bits, one uniform scalar load), hiding
// L3/HBM latency under the reduction. out is write-once -> nontemporal stores.
// NO min-waves bound: ra/rc alone is 64 VGPRs; a (256,4) bound would clamp to
// 64 VGPR and spill (round-6 lesson on mask).
// Bijection onto [0,S): selected -> p-1, unselected -> nsel + s - p.
__global__ __launch_bounds__(256) void scatter_kernel(
    const float* __restrict__ x, const unsigned int* __restrict__ cnt,
    float* __restrict__ out)
{
    __shared__ unsigned int lds_r[4];
    const int blk  = blockIdx.x;
    const int b    = blk >> 9;            // 512 scatter blocks per batch
    const int c8   = blk & 511;
    const int mc   = c8 >> 1;             // owning mask chunk (0..255)
    const int hf   = c8 & 1;              // which 8-token half
    const int t = threadIdx.x, lane = t & 63, wid = t >> 6;

    const unsigned int* cb = cnt + b * CPB;
    const unsigned vown   = cb[mc];                 // uniform -> scalar load
    const unsigned bits16 = vown >> 16;
    const unsigned bits   = (bits16 >> (8 * hf)) & 0xFFu;

    // issue the count load for the reduce (one per thread, covers all 256) ...
    const unsigned u = cb[t];

    // ... and the selected x rows, before the reduce completes
    const int s0 = c8 * SROWS;
    const float* xb = x + (size_t)b * SEQ * DIM;
    const int d0 = 4 * t, d1 = d0 + 1024;
    const float4 z = make_float4(0.f, 0.f, 0.f, 0.f);
    float4 ra[SROWS], rc[SROWS];
#pragma unroll
    for (int j = 0; j < SROWS; ++j) {
        if ((bits >> j) & 1) {                 // uniform branch
            const float* src = xb + (size_t)(s0 + j) * DIM;
            ra[j] = *(const float4*)(src + d0);
            rc[j] = *(const float4*)(src + d1);
        } else { ra[j] = z; rc[j] = z; }
    }

    // packed reduce: low16 = exclusive-prefix contribution, high16 = total
    const int c = (int)(u & 0xFFFFu);
    int pack = ((t < mc) ? c : 0) + (c << 16);
    pack = wave_sum_i(pack);
    if (lane == 0) lds_r[wid] = (unsigned)pack;
    __syncthreads();
    const unsigned tot = lds_r[0] + lds_r[1] + lds_r[2] + lds_r[3];
    const int pre  = (int)(tot & 0xFFFFu)
                   + (hf ? __popc(bits16 & 0xFFu) : 0);
    const int nsel = (int)(tot >> 16);

    float* ob = out + (size_t)b * SEQ * DIM;
#pragma unroll
    for (int j = 0; j < SROWS; ++j) {
        const int incl = __popc(bits & ((2u << j) - 1u));   // inclusive in 8
        const int p    = pre + incl;
        const int sel  = (bits >> j) & 1;
        const int dest = sel ? (p - 1) : (nsel + s0 + j - p);
        float* o = ob + (size_t)dest * DIM;
        __builtin_nontemporal_store(*(const f4*)&ra[j], (f4*)(o + d0));
        __builtin_nontemporal_store(*(const f4*)&rc[j], (f4*)(o + d1));
    }
}

extern "C" void kernel_launch(void* const* d_in, const int* in_sizes, int n_in,
                              void* d_out, int out_size, void* d_ws, size_t ws_size,
                              hipStream_t stream) {
    const float* x  = (const float*)d_in[0];   // [B,S,D]
    const float* nw = (const float*)d_in[1];   // [D]
    const float* cw = (const float*)d_in[2];   // [D,4]
    const float* pw = (const float*)d_in[3];   // [2,D]
    float* out = (float*)d_out;                // [B,S,D]

    unsigned int* cnt = (unsigned int*)d_ws;   // NBLK u32 = 4 KB; every entry
                                               // written by mask before scatter
                                               // reads -> no memset needed
    mask_kernel<<<NBLK, 256, 0, stream>>>(x, nw, cw, pw, cnt);
    scatter_kernel<<<NSCAT, 256, 0, stream>>>(x, cnt, out);
}